// Round 2
// baseline (171.885 us; speedup 1.0000x reference)
//
#include <hip/hip_runtime.h>
#include <hip/hip_bf16.h>

#define K_DIM 16384
#define M_DIM 512
#define N_DIM 2560

typedef float f32x4 __attribute__((ext_vector_type(4)));
typedef __bf16 bf16x8 __attribute__((ext_vector_type(8)));

__device__ __forceinline__ unsigned short f2bf(float f){
  union { float f; unsigned u; } v; v.f = f;
  unsigned r = v.u + 0x7FFFu + ((v.u >> 16) & 1u);
  return (unsigned short)(r >> 16);
}
__device__ __forceinline__ unsigned bfpack2(float lo, float hi){
  return (unsigned)f2bf(lo) | ((unsigned)f2bf(hi) << 16);
}

// K1: w_mean[c] = mean_f conv1_w[f][c]; b_mean = mean(conv1_b)
__global__ __launch_bounds__(256)
void prep_kernel(const float* __restrict__ conv1_w, const float* __restrict__ conv1_b,
                 float* __restrict__ w_mean, float* __restrict__ b_mean)
{
  int c = blockIdx.x * 256 + threadIdx.x;
  if (c < K_DIM){
    float s = 0.f;
    #pragma unroll
    for (int f = 0; f < 10; ++f) s += conv1_w[f * K_DIM + c];
    w_mean[c] = s * 0.1f;
  }
  if (blockIdx.x == 0 && threadIdx.x == 0){
    float s = 0.f;
    #pragma unroll
    for (int f = 0; f < 10; ++f) s += conv1_b[f];
    *b_mean = s * 0.1f;
  }
}

// K2: pooled[row] = x[row,:] . w_mean + b_mean   (one block per row)
__global__ __launch_bounds__(256)
void pooled_kernel(const float* __restrict__ X, const float* __restrict__ w_mean,
                   const float* __restrict__ b_mean, float* __restrict__ pooled)
{
  const int row = blockIdx.x;
  const int tid = threadIdx.x;
  const float* xr = X + (size_t)row * K_DIM;
  float s = 0.f;
  #pragma unroll 4
  for (int i = 0; i < 16; ++i){
    int idx = (tid + 256 * i) * 4;
    float4 a = *(const float4*)(xr + idx);
    float4 w = *(const float4*)(w_mean + idx);
    s += a.x*w.x + a.y*w.y + a.z*w.z + a.w*w.w;
  }
  #pragma unroll
  for (int off = 32; off; off >>= 1) s += __shfl_down(s, off);
  __shared__ float red[4];
  if ((tid & 63) == 0) red[tid >> 6] = s;
  __syncthreads();
  if (tid == 0) pooled[row] = red[0] + red[1] + red[2] + red[3] + *b_mean;
}

// K3: z = pooled @ ffnn1_w^T + b ; gates = w0*relu + w1*sigmoid + w2*softmax_T
__global__ __launch_bounds__(512)
void gates_kernel(const float* __restrict__ pooled, const float* __restrict__ fw,
                  const float* __restrict__ fb, const float* __restrict__ aw,
                  float* __restrict__ gates)
{
  __shared__ float ps[512];
  int tid = threadIdx.x;            // 512 threads: (b, s)
  ps[tid] = pooled[tid];
  __syncthreads();
  int b = tid >> 5, s = tid & 31;
  float z = fb[s];
  #pragma unroll
  for (int t = 0; t < 32; ++t) z += ps[b * 32 + t] * fw[s * 32 + t];
  // softmax over s within each b: b-groups = contiguous 32-lane halves of a wave
  float mx = z;
  #pragma unroll
  for (int off = 16; off; off >>= 1) mx = fmaxf(mx, __shfl_xor(mx, off));
  float e = expf(z - mx);
  float sum = e;
  #pragma unroll
  for (int off = 16; off; off >>= 1) sum += __shfl_xor(sum, off);
  float sm = e / sum;
  float relu = z > 0.f ? z : 0.f;
  float sig = 1.f / (1.f + expf(-z));
  gates[tid] = aw[0] * relu + aw[1] * sig + aw[2] * sm;
}

// K4: C[m,n] = x[m,:kchunk] . G3_w[n,:kchunk] for K-slice kz  (bf16 MFMA)
// mode 0: write raw partial to outp[kz*M*N + ...]; mode 2: atomicAdd into outp.
__global__ __launch_bounds__(256, 2)
void gemm_kernel(const float* __restrict__ X, const float* __restrict__ W,
                 float* __restrict__ outp, int kchunk, int mode)
{
  __shared__ uint4 smem4[2048];            // 32 KiB: As [0,16K), Bs [16K,32K)
  char* smem = (char*)smem4;

  const int tid  = threadIdx.x;
  const int lane = tid & 63;
  const int wv   = tid >> 6;
  const int wm   = (wv >> 1) * 64;
  const int wn   = (wv & 1) * 64;
  const int m0   = blockIdx.x * 128;
  const int n0   = blockIdx.y * 128;
  const int kz   = blockIdx.z;
  const int kbase = kz * kchunk;
  const int nk   = kchunk / 64;

  f32x4 acc[4][4] = {};
  float4 ra[4][2], rb[4][2];

  int srow[4], scc[4];
  #pragma unroll
  for (int j = 0; j < 4; ++j){ int q = j * 256 + tid; srow[j] = q >> 3; scc[j] = q & 7; }

  auto load_tile = [&](int k0){
    #pragma unroll
    for (int j = 0; j < 4; ++j){
      const float* pa = X + (size_t)(m0 + srow[j]) * K_DIM + k0 + scc[j] * 8;
      const float* pb = W + (size_t)(n0 + srow[j]) * K_DIM + k0 + scc[j] * 8;
      ra[j][0] = *(const float4*)pa;  ra[j][1] = *(const float4*)(pa + 4);
      rb[j][0] = *(const float4*)pb;  rb[j][1] = *(const float4*)(pb + 4);
    }
  };
  auto store_tile = [&](){
    #pragma unroll
    for (int j = 0; j < 4; ++j){
      int boff = srow[j] * 128 + ((scc[j] * 16) ^ ((srow[j] & 7) << 4));
      uint4 ua, ub;
      ua.x = bfpack2(ra[j][0].x, ra[j][0].y); ua.y = bfpack2(ra[j][0].z, ra[j][0].w);
      ua.z = bfpack2(ra[j][1].x, ra[j][1].y); ua.w = bfpack2(ra[j][1].z, ra[j][1].w);
      ub.x = bfpack2(rb[j][0].x, rb[j][0].y); ub.y = bfpack2(rb[j][0].z, rb[j][0].w);
      ub.z = bfpack2(rb[j][1].x, rb[j][1].y); ub.w = bfpack2(rb[j][1].z, rb[j][1].w);
      *(uint4*)(smem + boff) = ua;
      *(uint4*)(smem + 16384 + boff) = ub;
    }
  };

  load_tile(kbase);
  for (int kt = 0; kt < nk; ++kt){
    store_tile();
    __syncthreads();
    if (kt + 1 < nk) load_tile(kbase + (kt + 1) * 64);
    #pragma unroll
    for (int kk = 0; kk < 2; ++kk){
      bf16x8 af[4], bfr[4];
      int kbyt = (kk * 32 + (lane >> 4) * 8) * 2;
      #pragma unroll
      for (int i = 0; i < 4; ++i){
        int arow = wm + i * 16 + (lane & 15);
        af[i]  = *(const bf16x8*)(smem + arow * 128 + (kbyt ^ ((arow & 7) << 4)));
        int brow = wn + i * 16 + (lane & 15);
        bfr[i] = *(const bf16x8*)(smem + 16384 + brow * 128 + (kbyt ^ ((brow & 7) << 4)));
      }
      #pragma unroll
      for (int i = 0; i < 4; ++i)
        #pragma unroll
        for (int j2 = 0; j2 < 4; ++j2)
          acc[i][j2] = __builtin_amdgcn_mfma_f32_16x16x32_bf16(af[i], bfr[j2], acc[i][j2], 0, 0, 0);
    }
    __syncthreads();
  }

  if (mode == 0){
    float* P = outp + (size_t)kz * M_DIM * N_DIM;
    #pragma unroll
    for (int i = 0; i < 4; ++i){
      int rbase = m0 + wm + i * 16 + (lane >> 4) * 4;
      #pragma unroll
      for (int j2 = 0; j2 < 4; ++j2){
        int col = n0 + wn + j2 * 16 + (lane & 15);
        #pragma unroll
        for (int r = 0; r < 4; ++r)
          P[(size_t)(rbase + r) * N_DIM + col] = acc[i][j2][r];
      }
    }
  } else {
    #pragma unroll
    for (int i = 0; i < 4; ++i){
      int rbase = m0 + wm + i * 16 + (lane >> 4) * 4;
      #pragma unroll
      for (int j2 = 0; j2 < 4; ++j2){
        int col = n0 + wn + j2 * 16 + (lane & 15);
        #pragma unroll
        for (int r = 0; r < 4; ++r)
          atomicAdd(&outp[(size_t)(rbase + r) * N_DIM + col], acc[i][j2][r]);
      }
    }
  }
}

// K5a: out[m,n] = gates[m] * (sum_z partial[z,m,n] + bias[n])
__global__ __launch_bounds__(256)
void reduce_kernel(const float* __restrict__ part, const float* __restrict__ gates,
                   const float* __restrict__ bias, float* __restrict__ out, int ksplit)
{
  int i4 = blockIdx.x * 256 + threadIdx.x;
  if (i4 >= M_DIM * N_DIM / 4) return;
  size_t off = (size_t)i4 * 4;
  int m = (int)(off / N_DIM);
  int n = (int)(off % N_DIM);
  float sx = 0.f, sy = 0.f, sz = 0.f, sw = 0.f;
  for (int z = 0; z < ksplit; ++z){
    float4 p = *(const float4*)(part + (size_t)z * M_DIM * N_DIM + off);
    sx += p.x; sy += p.y; sz += p.z; sw += p.w;
  }
  float4 bv = *(const float4*)(bias + n);
  float g = gates[m];
  float4 o;
  o.x = g * (sx + bv.x); o.y = g * (sy + bv.y);
  o.z = g * (sz + bv.z); o.w = g * (sw + bv.w);
  *(float4*)(out + off) = o;
}

// K5b: in-place finalize after atomic accumulation: out = gates[m]*(out + bias[n])
__global__ __launch_bounds__(256)
void finalize_kernel(float* __restrict__ out, const float* __restrict__ gates,
                     const float* __restrict__ bias)
{
  int i4 = blockIdx.x * 256 + threadIdx.x;
  if (i4 >= M_DIM * N_DIM / 4) return;
  size_t off = (size_t)i4 * 4;
  int m = (int)(off / N_DIM);
  int n = (int)(off % N_DIM);
  float4 o = *(const float4*)(out + off);
  float4 bv = *(const float4*)(bias + n);
  float g = gates[m];
  o.x = g * (o.x + bv.x); o.y = g * (o.y + bv.y);
  o.z = g * (o.z + bv.z); o.w = g * (o.w + bv.w);
  *(float4*)(out + off) = o;
}

extern "C" void kernel_launch(void* const* d_in, const int* in_sizes, int n_in,
                              void* d_out, int out_size, void* d_ws, size_t ws_size,
                              hipStream_t stream)
{
  const float* input   = (const float*)d_in[0];
  const float* aw      = (const float*)d_in[2];
  const float* conv1_w = (const float*)d_in[3];
  const float* conv1_b = (const float*)d_in[4];
  const float* G3_w    = (const float*)d_in[5];
  const float* G3_b    = (const float*)d_in[6];
  const float* ffnn1_w = (const float*)d_in[7];
  const float* ffnn1_b = (const float*)d_in[8];
  float* out = (float*)d_out;

  float* wsf    = (float*)d_ws;
  float* w_mean = wsf;               // 16384
  float* pooled = wsf + 16384;       // 512
  float* gates  = wsf + 16896;       // 512
  float* b_mean = wsf + 17408;       // 1 (+pad)
  float* partial = wsf + 17472;      // ksplit * 512*2560

  const size_t base_bytes = 17472 * sizeof(float);
  const size_t part_bytes = (size_t)M_DIM * N_DIM * sizeof(float);

  prep_kernel<<<64, 256, 0, stream>>>(conv1_w, conv1_b, w_mean, b_mean);
  pooled_kernel<<<512, 256, 0, stream>>>(input, w_mean, b_mean, pooled);
  gates_kernel<<<1, 512, 0, stream>>>(pooled, ffnn1_w, ffnn1_b, aw, gates);

  const int n4 = M_DIM * N_DIM / 4;
  if (ws_size >= base_bytes + 8 * part_bytes){
    // deterministic split-K=8 via workspace partials: 640 blocks
    gemm_kernel<<<dim3(4, 20, 8), 256, 0, stream>>>(input, G3_w, partial, K_DIM / 8, 0);
    reduce_kernel<<<(n4 + 255) / 256, 256, 0, stream>>>(partial, gates, G3_b, out, 8);
  } else {
    // atomic split-K=4 into zeroed d_out: 320 blocks
    hipMemsetAsync(d_out, 0, (size_t)out_size * sizeof(float), stream);
    gemm_kernel<<<dim3(4, 20, 4), 256, 0, stream>>>(input, G3_w, out, K_DIM / 4, 2);
    finalize_kernel<<<(n4 + 255) / 256, 256, 0, stream>>>(out, gates, G3_b);
  }
}

// Round 3
// 148.133 us; speedup vs baseline: 1.1603x; 1.1603x over previous
//
#include <hip/hip_runtime.h>
#include <hip/hip_bf16.h>

#define K_DIM 16384
#define M_DIM 512
#define N_DIM 2560

typedef float f32x4 __attribute__((ext_vector_type(4)));
typedef __bf16 bf16x8 __attribute__((ext_vector_type(8)));

__device__ __forceinline__ unsigned short f2bf(float f){
  union { float f; unsigned u; } v; v.f = f;
  unsigned r = v.u + 0x7FFFu + ((v.u >> 16) & 1u);
  return (unsigned short)(r >> 16);
}
__device__ __forceinline__ unsigned bfpack2(float lo, float hi){
  return (unsigned)f2bf(lo) | ((unsigned)f2bf(hi) << 16);
}

// K1: w_mean[c] = mean_f conv1_w[f][c]; b_mean = mean(conv1_b)
__global__ __launch_bounds__(256)
void prep_kernel(const float* __restrict__ conv1_w, const float* __restrict__ conv1_b,
                 float* __restrict__ w_mean, float* __restrict__ b_mean)
{
  int c = blockIdx.x * 256 + threadIdx.x;
  if (c < K_DIM){
    float s = 0.f;
    #pragma unroll
    for (int f = 0; f < 10; ++f) s += conv1_w[f * K_DIM + c];
    w_mean[c] = s * 0.1f;
  }
  if (blockIdx.x == 0 && threadIdx.x == 0){
    float s = 0.f;
    #pragma unroll
    for (int f = 0; f < 10; ++f) s += conv1_b[f];
    *b_mean = s * 0.1f;
  }
}

// K2: pooled[row] = x[row,:] . w_mean + b_mean   (one block per row)
__global__ __launch_bounds__(256)
void pooled_kernel(const float* __restrict__ X, const float* __restrict__ w_mean,
                   const float* __restrict__ b_mean, float* __restrict__ pooled)
{
  const int row = blockIdx.x;
  const int tid = threadIdx.x;
  const float* xr = X + (size_t)row * K_DIM;
  float s = 0.f;
  #pragma unroll 4
  for (int i = 0; i < 16; ++i){
    int idx = (tid + 256 * i) * 4;
    float4 a = *(const float4*)(xr + idx);
    float4 w = *(const float4*)(w_mean + idx);
    s += a.x*w.x + a.y*w.y + a.z*w.z + a.w*w.w;
  }
  #pragma unroll
  for (int off = 32; off; off >>= 1) s += __shfl_down(s, off);
  __shared__ float red[4];
  if ((tid & 63) == 0) red[tid >> 6] = s;
  __syncthreads();
  if (tid == 0) pooled[row] = red[0] + red[1] + red[2] + red[3] + *b_mean;
}

// K3: z = pooled @ ffnn1_w^T + b ; gates = w0*relu + w1*sigmoid + w2*softmax_T
__global__ __launch_bounds__(512)
void gates_kernel(const float* __restrict__ pooled, const float* __restrict__ fw,
                  const float* __restrict__ fb, const float* __restrict__ aw,
                  float* __restrict__ gates)
{
  __shared__ float ps[512];
  int tid = threadIdx.x;            // 512 threads: (b, s)
  ps[tid] = pooled[tid];
  __syncthreads();
  int b = tid >> 5, s = tid & 31;
  float z = fb[s];
  #pragma unroll
  for (int t = 0; t < 32; ++t) z += ps[b * 32 + t] * fw[s * 32 + t];
  float mx = z;
  #pragma unroll
  for (int off = 16; off; off >>= 1) mx = fmaxf(mx, __shfl_xor(mx, off));
  float e = expf(z - mx);
  float sum = e;
  #pragma unroll
  for (int off = 16; off; off >>= 1) sum += __shfl_xor(sum, off);
  float sm = e / sum;
  float relu = z > 0.f ? z : 0.f;
  float sig = 1.f / (1.f + expf(-z));
  gates[tid] = aw[0] * relu + aw[1] * sig + aw[2] * sm;
}

// K4: C[m,n] = x[m,ksl] . G3_w[n,ksl]  (bf16 MFMA, fp32->bf16 on stage)
// Flat grid of 4*20*8 blocks. kz = blockIdx.x & 7 so that the dispatcher's
// round-robin (linear_id % 8 -> XCD) pins each K-slice to ONE XCD:
//   - X slice (512 x 2048 fp32 = 4 MB) becomes L2-resident per XCD
//   - the 4 blocks sharing a W-strip (same n0,kz; m0 = r&3) are consecutive
//     ids on the SAME XCD -> W-strip fetched from L3 once, not 4x.
// mode 0: write raw partial to outp[kz*M*N + ...]; mode 2: atomicAdd into outp.
__global__ __launch_bounds__(256, 2)
void gemm_kernel(const float* __restrict__ X, const float* __restrict__ W,
                 float* __restrict__ outp, int kchunk, int mode)
{
  __shared__ uint4 smem4[2048];            // 32 KiB: As [0,16K), Bs [16K,32K)
  char* smem = (char*)smem4;

  const int tid  = threadIdx.x;
  const int lane = tid & 63;
  const int wv   = tid >> 6;
  const int wm   = (wv >> 1) * 64;
  const int wn   = (wv & 1) * 64;

  const int id   = blockIdx.x;
  const int kz   = id & 7;          // XCD index == K-slice
  const int r    = id >> 3;         // 0..79 within XCD
  const int m0   = (r & 3) * 128;   // m0 fastest: W-strip sharers run together
  const int n0   = (r >> 2) * 128;

  const int kbase = kz * kchunk;
  const int nk   = kchunk / 64;

  f32x4 acc[4][4] = {};
  float4 ra[4][2], rb[4][2];

  int srow[4], scc[4];
  #pragma unroll
  for (int j = 0; j < 4; ++j){ int q = j * 256 + tid; srow[j] = q >> 3; scc[j] = q & 7; }

  auto load_tile = [&](int k0){
    #pragma unroll
    for (int j = 0; j < 4; ++j){
      const float* pa = X + (size_t)(m0 + srow[j]) * K_DIM + k0 + scc[j] * 8;
      const float* pb = W + (size_t)(n0 + srow[j]) * K_DIM + k0 + scc[j] * 8;
      ra[j][0] = *(const float4*)pa;  ra[j][1] = *(const float4*)(pa + 4);
      rb[j][0] = *(const float4*)pb;  rb[j][1] = *(const float4*)(pb + 4);
    }
  };
  auto store_tile = [&](){
    #pragma unroll
    for (int j = 0; j < 4; ++j){
      int boff = srow[j] * 128 + ((scc[j] * 16) ^ ((srow[j] & 7) << 4));
      uint4 ua, ub;
      ua.x = bfpack2(ra[j][0].x, ra[j][0].y); ua.y = bfpack2(ra[j][0].z, ra[j][0].w);
      ua.z = bfpack2(ra[j][1].x, ra[j][1].y); ua.w = bfpack2(ra[j][1].z, ra[j][1].w);
      ub.x = bfpack2(rb[j][0].x, rb[j][0].y); ub.y = bfpack2(rb[j][0].z, rb[j][0].w);
      ub.z = bfpack2(rb[j][1].x, rb[j][1].y); ub.w = bfpack2(rb[j][1].z, rb[j][1].w);
      *(uint4*)(smem + boff) = ua;
      *(uint4*)(smem + 16384 + boff) = ub;
    }
  };

  load_tile(kbase);
  for (int kt = 0; kt < nk; ++kt){
    store_tile();
    __syncthreads();
    if (kt + 1 < nk) load_tile(kbase + (kt + 1) * 64);
    #pragma unroll
    for (int kk = 0; kk < 2; ++kk){
      bf16x8 af[4], bfr[4];
      int kbyt = (kk * 32 + (lane >> 4) * 8) * 2;
      #pragma unroll
      for (int i = 0; i < 4; ++i){
        int arow = wm + i * 16 + (lane & 15);
        af[i]  = *(const bf16x8*)(smem + arow * 128 + (kbyt ^ ((arow & 7) << 4)));
        int brow = wn + i * 16 + (lane & 15);
        bfr[i] = *(const bf16x8*)(smem + 16384 + brow * 128 + (kbyt ^ ((brow & 7) << 4)));
      }
      #pragma unroll
      for (int i = 0; i < 4; ++i)
        #pragma unroll
        for (int j2 = 0; j2 < 4; ++j2)
          acc[i][j2] = __builtin_amdgcn_mfma_f32_16x16x32_bf16(af[i], bfr[j2], acc[i][j2], 0, 0, 0);
    }
    __syncthreads();
  }

  if (mode == 0){
    float* P = outp + (size_t)kz * M_DIM * N_DIM;
    #pragma unroll
    for (int i = 0; i < 4; ++i){
      int rbase = m0 + wm + i * 16 + (lane >> 4) * 4;
      #pragma unroll
      for (int j2 = 0; j2 < 4; ++j2){
        int col = n0 + wn + j2 * 16 + (lane & 15);
        #pragma unroll
        for (int r2 = 0; r2 < 4; ++r2)
          P[(size_t)(rbase + r2) * N_DIM + col] = acc[i][j2][r2];
      }
    }
  } else {
    #pragma unroll
    for (int i = 0; i < 4; ++i){
      int rbase = m0 + wm + i * 16 + (lane >> 4) * 4;
      #pragma unroll
      for (int j2 = 0; j2 < 4; ++j2){
        int col = n0 + wn + j2 * 16 + (lane & 15);
        #pragma unroll
        for (int r2 = 0; r2 < 4; ++r2)
          atomicAdd(&outp[(size_t)(rbase + r2) * N_DIM + col], acc[i][j2][r2]);
      }
    }
  }
}

// K5a: out[m,n] = gates[m] * (sum_z partial[z,m,n] + bias[n])
__global__ __launch_bounds__(256)
void reduce_kernel(const float* __restrict__ part, const float* __restrict__ gates,
                   const float* __restrict__ bias, float* __restrict__ out, int ksplit)
{
  int i4 = blockIdx.x * 256 + threadIdx.x;
  if (i4 >= M_DIM * N_DIM / 4) return;
  size_t off = (size_t)i4 * 4;
  int m = (int)(off / N_DIM);
  int n = (int)(off % N_DIM);
  float sx = 0.f, sy = 0.f, sz = 0.f, sw = 0.f;
  for (int z = 0; z < ksplit; ++z){
    float4 p = *(const float4*)(part + (size_t)z * M_DIM * N_DIM + off);
    sx += p.x; sy += p.y; sz += p.z; sw += p.w;
  }
  float4 bv = *(const float4*)(bias + n);
  float g = gates[m];
  float4 o;
  o.x = g * (sx + bv.x); o.y = g * (sy + bv.y);
  o.z = g * (sz + bv.z); o.w = g * (sw + bv.w);
  *(float4*)(out + off) = o;
}

// K5b: in-place finalize after atomic accumulation: out = gates[m]*(out + bias[n])
__global__ __launch_bounds__(256)
void finalize_kernel(float* __restrict__ out, const float* __restrict__ gates,
                     const float* __restrict__ bias)
{
  int i4 = blockIdx.x * 256 + threadIdx.x;
  if (i4 >= M_DIM * N_DIM / 4) return;
  size_t off = (size_t)i4 * 4;
  int m = (int)(off / N_DIM);
  int n = (int)(off % N_DIM);
  float4 o = *(const float4*)(out + off);
  float4 bv = *(const float4*)(bias + n);
  float g = gates[m];
  o.x = g * (o.x + bv.x); o.y = g * (o.y + bv.y);
  o.z = g * (o.z + bv.z); o.w = g * (o.w + bv.w);
  *(float4*)(out + off) = o;
}

extern "C" void kernel_launch(void* const* d_in, const int* in_sizes, int n_in,
                              void* d_out, int out_size, void* d_ws, size_t ws_size,
                              hipStream_t stream)
{
  const float* input   = (const float*)d_in[0];
  const float* aw      = (const float*)d_in[2];
  const float* conv1_w = (const float*)d_in[3];
  const float* conv1_b = (const float*)d_in[4];
  const float* G3_w    = (const float*)d_in[5];
  const float* G3_b    = (const float*)d_in[6];
  const float* ffnn1_w = (const float*)d_in[7];
  const float* ffnn1_b = (const float*)d_in[8];
  float* out = (float*)d_out;

  float* wsf    = (float*)d_ws;
  float* w_mean = wsf;               // 16384
  float* pooled = wsf + 16384;       // 512
  float* gates  = wsf + 16896;       // 512
  float* b_mean = wsf + 17408;       // 1 (+pad)
  float* partial = wsf + 17472;      // 8 * 512*2560

  const size_t base_bytes = 17472 * sizeof(float);
  const size_t part_bytes = (size_t)M_DIM * N_DIM * sizeof(float);

  prep_kernel<<<64, 256, 0, stream>>>(conv1_w, conv1_b, w_mean, b_mean);
  pooled_kernel<<<512, 256, 0, stream>>>(input, w_mean, b_mean, pooled);
  gates_kernel<<<1, 512, 0, stream>>>(pooled, ffnn1_w, ffnn1_b, aw, gates);

  const int n4 = M_DIM * N_DIM / 4;
  if (ws_size >= base_bytes + 8 * part_bytes){
    // deterministic split-K=8 via workspace partials: 640 blocks, kz pinned per XCD
    gemm_kernel<<<640, 256, 0, stream>>>(input, G3_w, partial, K_DIM / 8, 0);
    reduce_kernel<<<(n4 + 255) / 256, 256, 0, stream>>>(partial, gates, G3_b, out, 8);
  } else {
    // atomic split-K=8 into zeroed d_out (fallback; nondeterministic LSBs only)
    hipMemsetAsync(d_out, 0, (size_t)out_size * sizeof(float), stream);
    gemm_kernel<<<640, 256, 0, stream>>>(input, G3_w, out, K_DIM / 8, 2);
    finalize_kernel<<<(n4 + 255) / 256, 256, 0, stream>>>(out, gates, G3_b);
  }
}

// Round 4
// 108.928 us; speedup vs baseline: 1.5780x; 1.3599x over previous
//
#include <hip/hip_runtime.h>
#include <hip/hip_bf16.h>

#define K_DIM 16384
#define M_DIM 512
#define N_DIM 2560
#define BM 256
#define BN 256
#define BK 64
#define KSPLIT 8

typedef float f32x4 __attribute__((ext_vector_type(4)));
typedef __bf16 bf16x8 __attribute__((ext_vector_type(8)));

__device__ __forceinline__ unsigned short f2bf(float f){
  union { float f; unsigned u; } v; v.f = f;
  unsigned r = v.u + 0x7FFFu + ((v.u >> 16) & 1u);
  return (unsigned short)(r >> 16);
}
__device__ __forceinline__ unsigned bfpack2(float lo, float hi){
  return (unsigned)f2bf(lo) | ((unsigned)f2bf(hi) << 16);
}

// K1: w_mean[c] = mean_f conv1_w[f][c]; b_mean = mean(conv1_b)
__global__ __launch_bounds__(256)
void prep_kernel(const float* __restrict__ conv1_w, const float* __restrict__ conv1_b,
                 float* __restrict__ w_mean, float* __restrict__ b_mean)
{
  int c = blockIdx.x * 256 + threadIdx.x;
  if (c < K_DIM){
    float s = 0.f;
    #pragma unroll
    for (int f = 0; f < 10; ++f) s += conv1_w[f * K_DIM + c];
    w_mean[c] = s * 0.1f;
  }
  if (blockIdx.x == 0 && threadIdx.x == 0){
    float s = 0.f;
    #pragma unroll
    for (int f = 0; f < 10; ++f) s += conv1_b[f];
    *b_mean = s * 0.1f;
  }
}

// K2: pooled[row] = x[row,:].w_mean + b_mean  AND  xbf[row,:] = bf16(x[row,:])
__global__ __launch_bounds__(256)
void pooled_kernel(const float* __restrict__ X, const float* __restrict__ w_mean,
                   const float* __restrict__ b_mean, float* __restrict__ pooled,
                   unsigned short* __restrict__ xbf)
{
  const int row = blockIdx.x;
  const int tid = threadIdx.x;
  const float* xr = X + (size_t)row * K_DIM;
  unsigned short* xb = xbf + (size_t)row * K_DIM;
  float s = 0.f;
  #pragma unroll 2
  for (int i = 0; i < 8; ++i){
    int idx = (tid + 256 * i) * 8;
    float4 a0 = *(const float4*)(xr + idx);
    float4 a1 = *(const float4*)(xr + idx + 4);
    float4 w0 = *(const float4*)(w_mean + idx);
    float4 w1 = *(const float4*)(w_mean + idx + 4);
    s += a0.x*w0.x + a0.y*w0.y + a0.z*w0.z + a0.w*w0.w
       + a1.x*w1.x + a1.y*w1.y + a1.z*w1.z + a1.w*w1.w;
    uint4 p;
    p.x = bfpack2(a0.x, a0.y); p.y = bfpack2(a0.z, a0.w);
    p.z = bfpack2(a1.x, a1.y); p.w = bfpack2(a1.z, a1.w);
    *(uint4*)(xb + idx) = p;
  }
  #pragma unroll
  for (int off = 32; off; off >>= 1) s += __shfl_down(s, off);
  __shared__ float red[4];
  if ((tid & 63) == 0) red[tid >> 6] = s;
  __syncthreads();
  if (tid == 0) pooled[row] = red[0] + red[1] + red[2] + red[3] + *b_mean;
}

// K3: gates
__global__ __launch_bounds__(512)
void gates_kernel(const float* __restrict__ pooled, const float* __restrict__ fw,
                  const float* __restrict__ fb, const float* __restrict__ aw,
                  float* __restrict__ gates)
{
  __shared__ float ps[512];
  int tid = threadIdx.x;
  ps[tid] = pooled[tid];
  __syncthreads();
  int b = tid >> 5, s = tid & 31;
  float z = fb[s];
  #pragma unroll
  for (int t = 0; t < 32; ++t) z += ps[b * 32 + t] * fw[s * 32 + t];
  float mx = z;
  #pragma unroll
  for (int off = 16; off; off >>= 1) mx = fmaxf(mx, __shfl_xor(mx, off));
  float e = expf(z - mx);
  float sum = e;
  #pragma unroll
  for (int off = 16; off; off >>= 1) sum += __shfl_xor(sum, off);
  float sm = e / sum;
  float relu = z > 0.f ? z : 0.f;
  float sig = 1.f / (1.f + expf(-z));
  gates[tid] = aw[0] * relu + aw[1] * sig + aw[2] * sm;
}

// K4: 256x256 tile, 8 waves (2m x 4n), A = pre-converted bf16, B = fp32->bf16 on stage.
// Flat grid 160: kz = id&7 pins each K-slice to one XCD (X k-slice 2MB -> L2-resident).
// mode 0: raw partial per kz; mode 2: atomicAdd into outp.
__global__ __launch_bounds__(512, 2)
void gemm_kernel(const unsigned short* __restrict__ Abf, const float* __restrict__ W,
                 float* __restrict__ outp, int mode)
{
  __shared__ char smem[65536];          // A bf16 [256][64] swz (32KB) + B (32KB)
  const int tid  = threadIdx.x;
  const int lane = tid & 63;
  const int wv   = tid >> 6;
  const int wm   = (wv >> 2) * 128;     // 2 m-waves
  const int wn   = (wv & 3) * 64;       // 4 n-waves

  const int id = blockIdx.x;
  const int kz = id & 7;
  const int r  = id >> 3;               // 0..19
  const int m0 = (r & 1) * BM;          // m fastest: W-strip sharers adjacent
  const int n0 = (r >> 1) * BN;
  const int kbase = kz * (K_DIM / KSPLIT);
  const int nk = (K_DIM / KSPLIT) / BK; // 32

  f32x4 acc[8][4] = {};
  bf16x8 ra[4];
  float4 rb[4][2];

  int srow[4], scol[4];
  #pragma unroll
  for (int j = 0; j < 4; ++j){ int u = j * 512 + tid; srow[j] = u >> 3; scol[j] = u & 7; }

  auto load_tile = [&](int k0){
    #pragma unroll
    for (int j = 0; j < 4; ++j){
      ra[j] = *(const bf16x8*)(Abf + (size_t)(m0 + srow[j]) * K_DIM + k0 + scol[j] * 8);
      const float* pb = W + (size_t)(n0 + srow[j]) * K_DIM + k0 + scol[j] * 8;
      rb[j][0] = *(const float4*)pb;  rb[j][1] = *(const float4*)(pb + 4);
    }
  };
  auto store_tile = [&](){
    #pragma unroll
    for (int j = 0; j < 4; ++j){
      int boff = srow[j] * 128 + ((scol[j] * 16) ^ ((srow[j] & 7) << 4));
      *(bf16x8*)(smem + boff) = ra[j];
      uint4 ub;
      ub.x = bfpack2(rb[j][0].x, rb[j][0].y); ub.y = bfpack2(rb[j][0].z, rb[j][0].w);
      ub.z = bfpack2(rb[j][1].x, rb[j][1].y); ub.w = bfpack2(rb[j][1].z, rb[j][1].w);
      *(uint4*)(smem + 32768 + boff) = ub;
    }
  };

  load_tile(kbase);
  for (int kt = 0; kt < nk; ++kt){
    store_tile();
    __syncthreads();
    if (kt + 1 < nk) load_tile(kbase + (kt + 1) * BK);
    #pragma unroll
    for (int kk = 0; kk < 2; ++kk){
      bf16x8 af[8], bfv[4];
      int kbyte = kk * 64 + (lane >> 4) * 16;
      #pragma unroll
      for (int i = 0; i < 8; ++i){
        int row = wm + i * 16 + (lane & 15);
        af[i] = *(const bf16x8*)(smem + row * 128 + (kbyte ^ ((row & 7) << 4)));
      }
      #pragma unroll
      for (int j = 0; j < 4; ++j){
        int row = wn + j * 16 + (lane & 15);
        bfv[j] = *(const bf16x8*)(smem + 32768 + row * 128 + (kbyte ^ ((row & 7) << 4)));
      }
      #pragma unroll
      for (int i = 0; i < 8; ++i)
        #pragma unroll
        for (int j = 0; j < 4; ++j)
          acc[i][j] = __builtin_amdgcn_mfma_f32_16x16x32_bf16(af[i], bfv[j], acc[i][j], 0, 0, 0);
    }
    __syncthreads();
  }

  if (mode == 0){
    float* P = outp + (size_t)kz * M_DIM * N_DIM;
    #pragma unroll
    for (int i = 0; i < 8; ++i){
      int rbase = m0 + wm + i * 16 + (lane >> 4) * 4;
      #pragma unroll
      for (int j = 0; j < 4; ++j){
        int col = n0 + wn + j * 16 + (lane & 15);
        #pragma unroll
        for (int r2 = 0; r2 < 4; ++r2)
          P[(size_t)(rbase + r2) * N_DIM + col] = acc[i][j][r2];
      }
    }
  } else {
    #pragma unroll
    for (int i = 0; i < 8; ++i){
      int rbase = m0 + wm + i * 16 + (lane >> 4) * 4;
      #pragma unroll
      for (int j = 0; j < 4; ++j){
        int col = n0 + wn + j * 16 + (lane & 15);
        #pragma unroll
        for (int r2 = 0; r2 < 4; ++r2)
          atomicAdd(&outp[(size_t)(rbase + r2) * N_DIM + col], acc[i][j][r2]);
      }
    }
  }
}

// K5a: out[m,n] = gates[m] * (sum_z partial[z,m,n] + bias[n])
__global__ __launch_bounds__(256)
void reduce_kernel(const float* __restrict__ part, const float* __restrict__ gates,
                   const float* __restrict__ bias, float* __restrict__ out, int ksplit)
{
  int i4 = blockIdx.x * 256 + threadIdx.x;
  if (i4 >= M_DIM * N_DIM / 4) return;
  size_t off = (size_t)i4 * 4;
  int m = (int)(off / N_DIM);
  int n = (int)(off % N_DIM);
  float sx = 0.f, sy = 0.f, sz = 0.f, sw = 0.f;
  for (int z = 0; z < ksplit; ++z){
    float4 p = *(const float4*)(part + (size_t)z * M_DIM * N_DIM + off);
    sx += p.x; sy += p.y; sz += p.z; sw += p.w;
  }
  float4 bv = *(const float4*)(bias + n);
  float g = gates[m];
  float4 o;
  o.x = g * (sx + bv.x); o.y = g * (sy + bv.y);
  o.z = g * (sz + bv.z); o.w = g * (sw + bv.w);
  *(float4*)(out + off) = o;
}

// K5b: finalize after atomic accumulation
__global__ __launch_bounds__(256)
void finalize_kernel(float* __restrict__ out, const float* __restrict__ gates,
                     const float* __restrict__ bias)
{
  int i4 = blockIdx.x * 256 + threadIdx.x;
  if (i4 >= M_DIM * N_DIM / 4) return;
  size_t off = (size_t)i4 * 4;
  int m = (int)(off / N_DIM);
  int n = (int)(off % N_DIM);
  float4 o = *(const float4*)(out + off);
  float4 bv = *(const float4*)(bias + n);
  float g = gates[m];
  o.x = g * (o.x + bv.x); o.y = g * (o.y + bv.y);
  o.z = g * (o.z + bv.z); o.w = g * (o.w + bv.w);
  *(float4*)(out + off) = o;
}

extern "C" void kernel_launch(void* const* d_in, const int* in_sizes, int n_in,
                              void* d_out, int out_size, void* d_ws, size_t ws_size,
                              hipStream_t stream)
{
  const float* input   = (const float*)d_in[0];
  const float* aw      = (const float*)d_in[2];
  const float* conv1_w = (const float*)d_in[3];
  const float* conv1_b = (const float*)d_in[4];
  const float* G3_w    = (const float*)d_in[5];
  const float* G3_b    = (const float*)d_in[6];
  const float* ffnn1_w = (const float*)d_in[7];
  const float* ffnn1_b = (const float*)d_in[8];
  float* out = (float*)d_out;

  float* wsf    = (float*)d_ws;
  float* w_mean = wsf;               // 16384 f
  float* pooled = wsf + 16384;       // 512 f
  float* gates  = wsf + 16896;       // 512 f
  float* b_mean = wsf + 17408;       // 64 f pad
  unsigned short* xbf = (unsigned short*)(wsf + 17472);        // 512*16384 bf16 = 16MB
  float* partial = wsf + 17472 + (size_t)M_DIM * K_DIM / 2;    // 8 * 512*2560 f

  const size_t need_det = ((size_t)17472 + (size_t)M_DIM * K_DIM / 2
                           + (size_t)KSPLIT * M_DIM * N_DIM) * 4;   // ~58.9MB
  prep_kernel<<<64, 256, 0, stream>>>(conv1_w, conv1_b, w_mean, b_mean);
  pooled_kernel<<<512, 256, 0, stream>>>(input, w_mean, b_mean, pooled, xbf);
  gates_kernel<<<1, 512, 0, stream>>>(pooled, ffnn1_w, ffnn1_b, aw, gates);

  const int n4 = M_DIM * N_DIM / 4;
  if (ws_size >= need_det){
    gemm_kernel<<<2 * 10 * KSPLIT, 512, 0, stream>>>(xbf, G3_w, partial, 0);
    reduce_kernel<<<(n4 + 255) / 256, 256, 0, stream>>>(partial, gates, G3_b, out, KSPLIT);
  } else {
    hipMemsetAsync(d_out, 0, (size_t)out_size * sizeof(float), stream);
    gemm_kernel<<<2 * 10 * KSPLIT, 512, 0, stream>>>(xbf, G3_w, out, 2);
    finalize_kernel<<<(n4 + 255) / 256, 256, 0, stream>>>(out, gates, G3_b);
  }
}